// Round 1
// baseline (13330.432 us; speedup 1.0000x reference)
//
#include <hip/hip_runtime.h>
#include <math.h>

#define D_IN    1024
#define D_CELL  2048
#define T_STEPS 2048
#define D_Z     3072            // D_IN + D_CELL
#define R_TOTAL (4 * D_CELL)    // 8192 gate rows
#define NBLK    256
#define NTHR    512

typedef unsigned long long u64;

// ---------------------------------------------------------------------------
// init: zero the h-exchange slots (harness does NOT re-poison ws between
// timed replays; stale tags from a previous replay would satisfy polls).
// slots = u64[2][D_CELL], slot = (tag<<32)|f32bits(h)
// ---------------------------------------------------------------------------
__global__ void lstm_init_kernel(u64* __restrict__ slots) {
    int i = blockIdx.x * 256 + threadIdx.x;
    if (i < 2 * D_CELL) slots[i] = 0ull;
}

// ---------------------------------------------------------------------------
// Gx[r][t] = b[r] + sum_k W_g[d][k] * x[k][t]   (k < 1024, input part)
// 1D grid of 2048 blocks, XCD-aware decode: each XCD works on ONE t-half
// (same 4 MiB x tile -> fits its private 4 MiB L2). 256 threads, each
// handles 4 t-columns x 8 rows. W row loads are wave-uniform -> s_load.
// ---------------------------------------------------------------------------
__global__ __launch_bounds__(256) void lstm_gx_kernel(
    const float* __restrict__ Wf, const float* __restrict__ bf,
    const float* __restrict__ Wi, const float* __restrict__ bi,
    const float* __restrict__ Wc, const float* __restrict__ bc,
    const float* __restrict__ Wo, const float* __restrict__ bo,
    const float* __restrict__ x,  float* __restrict__ Gx)
{
    const int bid = blockIdx.x;          // 0..2047
    const int xcd = bid & 7;             // HW round-robin: bid%8 = XCD
    const int loc = bid >> 3;            // 0..255
    const int tx  = xcd >> 2;            // t-half 0/1 (4 XCDs per half)
    const int yb  = (xcd & 3) * 256 + loc;   // row-block 0..1023
    const int tid = threadIdx.x;
    const int t0  = tx * 1024 + tid * 4;
    const int r0  = yb * 8;
    const int g   = r0 >> 11;
    const int d0  = r0 & 2047;
    const float* W = (g == 0) ? Wf : (g == 1) ? Wi : (g == 2) ? Wc : Wo;
    const float* b = (g == 0) ? bf : (g == 1) ? bi : (g == 2) ? bc : bo;

    const float* wr0 = W + (size_t)(d0 + 0) * D_Z;
    const float* wr1 = W + (size_t)(d0 + 1) * D_Z;
    const float* wr2 = W + (size_t)(d0 + 2) * D_Z;
    const float* wr3 = W + (size_t)(d0 + 3) * D_Z;
    const float* wr4 = W + (size_t)(d0 + 4) * D_Z;
    const float* wr5 = W + (size_t)(d0 + 5) * D_Z;
    const float* wr6 = W + (size_t)(d0 + 6) * D_Z;
    const float* wr7 = W + (size_t)(d0 + 7) * D_Z;

    float4 acc[8];
#pragma unroll
    for (int jr = 0; jr < 8; ++jr) acc[jr] = make_float4(0.f, 0.f, 0.f, 0.f);

    for (int k = 0; k < D_IN; k += 4) {
        float4 xa = *(const float4*)(x + (size_t)(k + 0) * T_STEPS + t0);
        float4 xb = *(const float4*)(x + (size_t)(k + 1) * T_STEPS + t0);
        float4 xc = *(const float4*)(x + (size_t)(k + 2) * T_STEPS + t0);
        float4 xd = *(const float4*)(x + (size_t)(k + 3) * T_STEPS + t0);
        const float* wrs[8] = {wr0, wr1, wr2, wr3, wr4, wr5, wr6, wr7};
#pragma unroll
        for (int jr = 0; jr < 8; ++jr) {
            float4 w = *(const float4*)(wrs[jr] + k);   // wave-uniform
            acc[jr].x += w.x * xa.x + w.y * xb.x + w.z * xc.x + w.w * xd.x;
            acc[jr].y += w.x * xa.y + w.y * xb.y + w.z * xc.y + w.w * xd.y;
            acc[jr].z += w.x * xa.z + w.y * xb.z + w.z * xc.z + w.w * xd.z;
            acc[jr].w += w.x * xa.w + w.y * xb.w + w.z * xc.w + w.w * xd.w;
        }
    }

#pragma unroll
    for (int jr = 0; jr < 8; ++jr) {
        float bb = b[d0 + jr];
        float4 o = acc[jr];
        o.x += bb; o.y += bb; o.z += bb; o.w += bb;
        *(float4*)(Gx + (size_t)(r0 + jr) * T_STEPS + t0) = o;
    }
}

// ---------------------------------------------------------------------------
// Persistent recurrence kernel. grid = 256 blocks (1/CU), block = 512 (8
// waves). Each WAVE owns one full cell: 4 gate rows x 2048, lane l holds
// k-slice {j*256 + l*4} for j=0..7 of all 4 rows (128 weight VGPRs). The
// 4 gate sums reduce fully IN-WAVE (6 butterflies + 4 parallel broadcasts),
// activations are computed redundantly per-lane -> no cross-wave hop, no
// second barrier. hs double-buffered in LDS -> ONE __syncthreads per step.
// Each lane polls its own 4 h-slots with one batched 4-load tag check.
// ---------------------------------------------------------------------------
__global__ __launch_bounds__(NTHR, 2) void lstm_rec_kernel(
    const float* __restrict__ Wf, const float* __restrict__ Wi,
    const float* __restrict__ Wc, const float* __restrict__ Wo,
    const float* __restrict__ Gx, u64* __restrict__ slots,
    float* __restrict__ out)
{
    __shared__ float hs[2][D_CELL];      // h_{t-1}, double-buffered

    const int tid  = threadIdx.x;
    const int w    = tid >> 6;           // wave 0..7 == local cell
    const int lane = tid & 63;
    const int d    = blockIdx.x * 8 + w; // global cell

    // ---- load my 4 gate rows (recurrent part), fp32, stay in VGPRs ----
    const float* bse0 = Wf + (size_t)d * D_Z + D_IN;
    const float* bse1 = Wi + (size_t)d * D_Z + D_IN;
    const float* bse2 = Wc + (size_t)d * D_Z + D_IN;
    const float* bse3 = Wo + (size_t)d * D_Z + D_IN;
    float4 wg0[8], wg1[8], wg2[8], wg3[8];
#pragma unroll
    for (int j = 0; j < 8; ++j) {
        wg0[j] = *(const float4*)(bse0 + j * 256 + lane * 4);
        wg1[j] = *(const float4*)(bse1 + j * 256 + lane * 4);
        wg2[j] = *(const float4*)(bse2 + j * 256 + lane * 4);
        wg3[j] = *(const float4*)(bse3 + j * 256 + lane * 4);
    }

    // Gx row for lanes 0..3 (gate = lane)
    const size_t gxbase = (size_t)((lane & 3) * D_CELL + d) * T_STEPS;

    // polling slice: slots for h[w*256 + lane*4 .. +3]
    const int sidx = w * 256 + lane * 4;

    float c = 0.f;

    for (int t = 0; t < T_STEPS; ++t) {
        // prefetch Gx early (independent of poll)
        float gx = 0.f;
        if (lane < 4) gx = Gx[gxbase + t];

        const int par = t & 1;
        if (t == 0) {
            *(float4*)&hs[0][sidx] = make_float4(0.f, 0.f, 0.f, 0.f);
        } else {
            const u64* bp = slots + (size_t)par * D_CELL + sidx;
            const u64 tg = (u64)(unsigned)t << 32;
            u64 s0, s1, s2, s3;
            for (;;) {
                s0 = __hip_atomic_load(bp + 0, __ATOMIC_RELAXED, __HIP_MEMORY_SCOPE_AGENT);
                s1 = __hip_atomic_load(bp + 1, __ATOMIC_RELAXED, __HIP_MEMORY_SCOPE_AGENT);
                s2 = __hip_atomic_load(bp + 2, __ATOMIC_RELAXED, __HIP_MEMORY_SCOPE_AGENT);
                s3 = __hip_atomic_load(bp + 3, __ATOMIC_RELAXED, __HIP_MEMORY_SCOPE_AGENT);
                u64 m = ((s0 ^ tg) | (s1 ^ tg) | (s2 ^ tg) | (s3 ^ tg)) >> 32;
                if (m == 0) break;
                __builtin_amdgcn_s_sleep(1);
            }
            float4 hv;
            hv.x = __uint_as_float((unsigned)s0);
            hv.y = __uint_as_float((unsigned)s1);
            hv.z = __uint_as_float((unsigned)s2);
            hv.w = __uint_as_float((unsigned)s3);
            *(float4*)&hs[par][sidx] = hv;
        }
        __syncthreads();                 // single barrier per step

        // ---- 4 gate-row dot slices from VGPR weights ----
        float a0 = 0.f, a1 = 0.f, a2 = 0.f, a3 = 0.f;
#pragma unroll
        for (int j = 0; j < 8; ++j) {
            float4 h = *(const float4*)&hs[par][j * 256 + lane * 4];
            a0 += wg0[j].x * h.x + wg0[j].y * h.y + wg0[j].z * h.z + wg0[j].w * h.w;
            a1 += wg1[j].x * h.x + wg1[j].y * h.y + wg1[j].z * h.z + wg1[j].w * h.w;
            a2 += wg2[j].x * h.x + wg2[j].y * h.y + wg2[j].z * h.z + wg2[j].w * h.w;
            a3 += wg3[j].x * h.x + wg3[j].y * h.y + wg3[j].z * h.z + wg3[j].w * h.w;
        }

        // ---- in-wave 4-value butterfly reduce: lane%4==g holds gate-g sum ----
        float p01a = (lane & 1) ? a1 : a0;
        float p01b = (lane & 1) ? a0 : a1;
        float v01  = p01a + __shfl_xor(p01b, 1);
        float p23a = (lane & 1) ? a3 : a2;
        float p23b = (lane & 1) ? a2 : a3;
        float v23  = p23a + __shfl_xor(p23b, 1);
        float qa = (lane & 2) ? v23 : v01;
        float qb = (lane & 2) ? v01 : v23;
        float u  = qa + __shfl_xor(qb, 2);
        u += __shfl_xor(u, 4);
        u += __shfl_xor(u, 8);
        u += __shfl_xor(u, 16);
        u += __shfl_xor(u, 32);
        u += gx;                         // valid in lanes 0..3 (gx=0 elsewhere)

        // 4 independent broadcasts (not a chain)
        float gf = __shfl(u, 0);
        float gi = __shfl(u, 1);
        float gc = __shfl(u, 2);
        float go = __shfl(u, 3);

        // ---- fast activations (v_exp_f32 / v_rcp_f32), all lanes redundant ----
        const float L2E  = 1.442695041f;     // log2(e)
        const float L2E2 = 2.885390082f;     // 2*log2(e)
        float f  = __builtin_amdgcn_rcpf(1.f + __builtin_amdgcn_exp2f(-L2E * gf));
        float ig = __builtin_amdgcn_rcpf(1.f + __builtin_amdgcn_exp2f(-L2E * gi));
        float o  = __builtin_amdgcn_rcpf(1.f + __builtin_amdgcn_exp2f(-L2E * go));
        float ec = __builtin_amdgcn_exp2f(L2E2 * gc);
        float cand = 1.f - 2.f * __builtin_amdgcn_rcpf(ec + 1.f);
        c = f * c + ig * cand;
        float eh = __builtin_amdgcn_exp2f(L2E2 * c);
        float tc = 1.f - 2.f * __builtin_amdgcn_rcpf(eh + 1.f);
        float hn = o * tc;

        if (lane == 0) {
            if (t + 1 < T_STEPS) {       // publish FIRST, then out-store
                u64 pk = ((u64)(unsigned)(t + 1) << 32)
                       | (u64)__float_as_uint(hn);
                __hip_atomic_store(
                    slots + (size_t)((t + 1) & 1) * D_CELL + d,
                    pk, __ATOMIC_RELAXED, __HIP_MEMORY_SCOPE_AGENT);
            }
            out[(size_t)d * T_STEPS + t] = hn;
        }
    }
}

// ---------------------------------------------------------------------------
extern "C" void kernel_launch(void* const* d_in, const int* in_sizes, int n_in,
                              void* d_out, int out_size, void* d_ws, size_t ws_size,
                              hipStream_t stream) {
    const float* x  = (const float*)d_in[0];
    const float* Wf = (const float*)d_in[1];
    const float* bf = (const float*)d_in[2];
    const float* Wi = (const float*)d_in[3];
    const float* bi = (const float*)d_in[4];
    const float* Wc = (const float*)d_in[5];
    const float* bc = (const float*)d_in[6];
    const float* Wo = (const float*)d_in[7];
    const float* bo = (const float*)d_in[8];
    float* out = (float*)d_out;

    // ws layout: Gx fp32 [8192][2048] | slots u64 [2][2048]
    const size_t gx_elems = (size_t)R_TOTAL * T_STEPS;
    const size_t need = gx_elems * 4 + 2 * D_CELL * 8;
    if (ws_size < need) return;
    float* Gx    = (float*)d_ws;
    u64*   slots = (u64*)(Gx + gx_elems);

    lstm_init_kernel<<<16, 256, 0, stream>>>(slots);

    lstm_gx_kernel<<<2048, 256, 0, stream>>>(Wf, bf, Wi, bi, Wc, bc, Wo, bo,
                                             x, Gx);

    lstm_rec_kernel<<<NBLK, NTHR, 0, stream>>>(Wf, Wi, Wc, Wo, Gx, slots, out);
}

// Round 2
// 11231.182 us; speedup vs baseline: 1.1869x; 1.1869x over previous
//
#include <hip/hip_runtime.h>
#include <math.h>

#define D_IN    1024
#define D_CELL  2048
#define T_STEPS 2048
#define D_Z     3072            // D_IN + D_CELL
#define R_TOTAL (4 * D_CELL)    // 8192 gate rows
#define NBLK    256
#define NTHR    1024

typedef unsigned long long u64;

// Force a float4 to stay materialized in VGPRs (defeats rematerialization:
// the compiler must treat the values as modified and cannot re-load them).
#define KEEP4(v) asm volatile("" : "+v"((v).x), "+v"((v).y), "+v"((v).z), "+v"((v).w))

// ---------------------------------------------------------------------------
// init: zero the h-exchange slots (harness does NOT re-poison ws between
// timed replays; stale tags from a previous replay would satisfy polls).
// slots = u64[2][D_CELL], slot = (tag<<32)|f32bits(h)
// ---------------------------------------------------------------------------
__global__ void lstm_init_kernel(u64* __restrict__ slots) {
    int i = blockIdx.x * 256 + threadIdx.x;
    if (i < 2 * D_CELL) slots[i] = 0ull;
}

// ---------------------------------------------------------------------------
// Gx[r][t] = b[r] + sum_k W_g[d][k] * x[k][t]   (k < 1024, input part)
// 1D grid of 2048 blocks, XCD-aware decode: each XCD works on ONE t-half
// (same 4 MiB x tile -> fits its private 4 MiB L2). 256 threads, each
// handles 4 t-columns x 8 rows. W row loads are wave-uniform -> s_load.
// ---------------------------------------------------------------------------
__global__ __launch_bounds__(256) void lstm_gx_kernel(
    const float* __restrict__ Wf, const float* __restrict__ bf,
    const float* __restrict__ Wi, const float* __restrict__ bi,
    const float* __restrict__ Wc, const float* __restrict__ bc,
    const float* __restrict__ Wo, const float* __restrict__ bo,
    const float* __restrict__ x,  float* __restrict__ Gx)
{
    const int bid = blockIdx.x;          // 0..2047
    const int xcd = bid & 7;             // HW round-robin: bid%8 = XCD
    const int loc = bid >> 3;            // 0..255
    const int tx  = xcd >> 2;            // t-half 0/1 (4 XCDs per half)
    const int yb  = (xcd & 3) * 256 + loc;   // row-block 0..1023
    const int tid = threadIdx.x;
    const int t0  = tx * 1024 + tid * 4;
    const int r0  = yb * 8;
    const int g   = r0 >> 11;
    const int d0  = r0 & 2047;
    const float* W = (g == 0) ? Wf : (g == 1) ? Wi : (g == 2) ? Wc : Wo;
    const float* b = (g == 0) ? bf : (g == 1) ? bi : (g == 2) ? bc : bo;

    const float* wr0 = W + (size_t)(d0 + 0) * D_Z;
    const float* wr1 = W + (size_t)(d0 + 1) * D_Z;
    const float* wr2 = W + (size_t)(d0 + 2) * D_Z;
    const float* wr3 = W + (size_t)(d0 + 3) * D_Z;
    const float* wr4 = W + (size_t)(d0 + 4) * D_Z;
    const float* wr5 = W + (size_t)(d0 + 5) * D_Z;
    const float* wr6 = W + (size_t)(d0 + 6) * D_Z;
    const float* wr7 = W + (size_t)(d0 + 7) * D_Z;

    float4 acc[8];
#pragma unroll
    for (int jr = 0; jr < 8; ++jr) acc[jr] = make_float4(0.f, 0.f, 0.f, 0.f);

    for (int k = 0; k < D_IN; k += 4) {
        float4 xa = *(const float4*)(x + (size_t)(k + 0) * T_STEPS + t0);
        float4 xb = *(const float4*)(x + (size_t)(k + 1) * T_STEPS + t0);
        float4 xc = *(const float4*)(x + (size_t)(k + 2) * T_STEPS + t0);
        float4 xd = *(const float4*)(x + (size_t)(k + 3) * T_STEPS + t0);
        const float* wrs[8] = {wr0, wr1, wr2, wr3, wr4, wr5, wr6, wr7};
#pragma unroll
        for (int jr = 0; jr < 8; ++jr) {
            float4 w = *(const float4*)(wrs[jr] + k);   // wave-uniform
            acc[jr].x += w.x * xa.x + w.y * xb.x + w.z * xc.x + w.w * xd.x;
            acc[jr].y += w.x * xa.y + w.y * xb.y + w.z * xc.y + w.w * xd.y;
            acc[jr].z += w.x * xa.z + w.y * xb.z + w.z * xc.z + w.w * xd.z;
            acc[jr].w += w.x * xa.w + w.y * xb.w + w.z * xc.w + w.w * xd.w;
        }
    }

#pragma unroll
    for (int jr = 0; jr < 8; ++jr) {
        float bb = b[d0 + jr];
        float4 o = acc[jr];
        o.x += bb; o.y += bb; o.z += bb; o.w += bb;
        *(float4*)(Gx + (size_t)(r0 + jr) * T_STEPS + t0) = o;
    }
}

// ---------------------------------------------------------------------------
// Persistent recurrence kernel. grid = 256 (one block per CU), block = 1024
// (16 waves, ~100 VGPR -> all 16 resident, 50% occupancy). Wave w owns gate
// rows {2w, 2w+1} (cell w>>1); lane l owns k-slice {j*256 + l*4} j=0..7.
// Weights are loaded ONCE and pinned in VGPRs via KEEP4 (round-1 post-mortem:
// without this the compiler rematerializes the loads every step -> 256 KB/
// step/block of L2/LLC traffic, FETCH_SIZE 2x, step time 2x).
// Per step: batched 2-slot poll -> hs in LDS -> sync A -> dot from VGPR
// weights -> paired butterfly -> gdot -> sync B -> wave w<8 computes cell w's
// activation redundantly on all lanes (fast exp2/rcp), lane 0 publishes slot
// FIRST then stores out. Waves 8..15 run ahead into the t+1 poll.
// ---------------------------------------------------------------------------
__global__ __launch_bounds__(NTHR, 4) void lstm_rec_kernel(
    const float* __restrict__ Wf, const float* __restrict__ Wi,
    const float* __restrict__ Wc, const float* __restrict__ Wo,
    const float* __restrict__ Gx, u64* __restrict__ slots,
    float* __restrict__ out)
{
    __shared__ float hs[2][D_CELL];  // h_{t-1}, double-buffered
    __shared__ float gdot[32];       // per-row reduced dots

    const int tid  = threadIdx.x;
    const int w    = tid >> 6;       // wave 0..15
    const int lane = tid & 63;
    const int r0   = 2 * w;          // local rows r0, r0+1 (row = cell*4+gate)

    // ---- load my two weight rows (recurrent part), pin in VGPRs ----
    const int g0 = r0 & 3,        g1 = (r0 + 1) & 3;
    const int cl = r0 >> 2;                       // same cell for both rows
    const int d  = blockIdx.x * 8 + cl;           // global cell (dot role)
    const float* Wb0 = ((g0 == 0) ? Wf : (g0 == 1) ? Wi : (g0 == 2) ? Wc : Wo)
                       + (size_t)d * D_Z + D_IN;
    const float* Wb1 = ((g1 == 0) ? Wf : (g1 == 1) ? Wi : (g1 == 2) ? Wc : Wo)
                       + (size_t)d * D_Z + D_IN;
    float4 wA[8], wB[8];
#pragma unroll
    for (int j = 0; j < 8; ++j) {
        wA[j] = *(const float4*)(Wb0 + j * 256 + lane * 4);
        wB[j] = *(const float4*)(Wb1 + j * 256 + lane * 4);
    }
#pragma unroll
    for (int j = 0; j < 8; ++j) { KEEP4(wA[j]); KEEP4(wB[j]); }

    // Gx row base for lanes 0,1 (lane L prefetches row r0+L)
    const int myrow = r0 + (lane & 1);
    const size_t gxbase = (size_t)((myrow & 3) * D_CELL
                                   + blockIdx.x * 8 + (myrow >> 2)) * T_STEPS;

    const int dact = blockIdx.x * 8 + w;   // activation role: wave w<8 = cell w
    float c = 0.f;
    const float L2E  = 1.442695041f;       // log2(e)
    const float L2E2 = 2.885390082f;       // 2*log2(e)

    for (int t = 0; t < T_STEPS; ++t) {
        // prefetch Gx early (independent of poll)
        float gx = 0.f;
        if (lane < 2) gx = Gx[gxbase + t];

        const int par = t & 1;
        if (t == 0) {
            *(float2*)&hs[0][2 * tid] = make_float2(0.f, 0.f);
        } else {
            // batched poll of my 2 slots: one combined tag check
            const u64* bp = slots + (size_t)par * D_CELL + 2 * tid;
            const u64 tg = (u64)(unsigned)t << 32;
            u64 a, b;
            for (;;) {
                a = __hip_atomic_load(bp + 0, __ATOMIC_RELAXED,
                                      __HIP_MEMORY_SCOPE_AGENT);
                b = __hip_atomic_load(bp + 1, __ATOMIC_RELAXED,
                                      __HIP_MEMORY_SCOPE_AGENT);
                if ((((a ^ tg) | (b ^ tg)) >> 32) == 0) break;
                __builtin_amdgcn_s_sleep(1);
            }
            *(float2*)&hs[par][2 * tid] =
                make_float2(__uint_as_float((unsigned)a),
                            __uint_as_float((unsigned)b));
        }
        __syncthreads();                          // sync A: hs ready

        // ---- two gate-row dot slices from pinned VGPR weights ----
        float acc0 = 0.f, acc1 = 0.f;
#pragma unroll
        for (int j = 0; j < 8; ++j) {
            float4 h = *(const float4*)&hs[par][j * 256 + lane * 4];
            acc0 += wA[j].x * h.x + wA[j].y * h.y + wA[j].z * h.z + wA[j].w * h.w;
            acc1 += wB[j].x * h.x + wB[j].y * h.y + wB[j].z * h.z + wB[j].w * h.w;
        }
        // paired butterfly: even lanes -> row r0 sum, odd lanes -> row r0+1
        float vK = (lane & 1) ? acc1 : acc0;
        float vO = (lane & 1) ? acc0 : acc1;
        float v  = vK + __shfl_xor(vO, 1);
        v += __shfl_xor(v, 2);
        v += __shfl_xor(v, 4);
        v += __shfl_xor(v, 8);
        v += __shfl_xor(v, 16);
        v += __shfl_xor(v, 32);
        if (lane < 2) gdot[r0 + lane] = v + gx;
        __syncthreads();                          // sync B: gdot ready

        // ---- activations: wave w<8 handles cell w, all lanes redundant ----
        if (w < 8) {
            float gf = gdot[4 * w + 0], gi = gdot[4 * w + 1];
            float gc = gdot[4 * w + 2], go = gdot[4 * w + 3];
            float f    = __builtin_amdgcn_rcpf(
                             1.f + __builtin_amdgcn_exp2f(-L2E * gf));
            float ig   = __builtin_amdgcn_rcpf(
                             1.f + __builtin_amdgcn_exp2f(-L2E * gi));
            float o    = __builtin_amdgcn_rcpf(
                             1.f + __builtin_amdgcn_exp2f(-L2E * go));
            float cand = 1.f - 2.f * __builtin_amdgcn_rcpf(
                             __builtin_amdgcn_exp2f(L2E2 * gc) + 1.f);
            c = f * c + ig * cand;
            float tc   = 1.f - 2.f * __builtin_amdgcn_rcpf(
                             __builtin_amdgcn_exp2f(L2E2 * c) + 1.f);
            float hn = o * tc;
            if (lane == 0) {
                if (t + 1 < T_STEPS) {            // publish FIRST
                    u64 pk = ((u64)(unsigned)(t + 1) << 32)
                           | (u64)__float_as_uint(hn);
                    __hip_atomic_store(
                        slots + (size_t)((t + 1) & 1) * D_CELL + dact,
                        pk, __ATOMIC_RELAXED, __HIP_MEMORY_SCOPE_AGENT);
                }
                out[(size_t)dact * T_STEPS + t] = hn;
            }
        }
        // no third sync: hs[par^1] writes for t+1 are to the other buffer;
        // gdot writes for t+1 happen only after sync A(t+1), by which time
        // the activation waves have consumed gdot(t).
    }
}

// ---------------------------------------------------------------------------
extern "C" void kernel_launch(void* const* d_in, const int* in_sizes, int n_in,
                              void* d_out, int out_size, void* d_ws, size_t ws_size,
                              hipStream_t stream) {
    const float* x  = (const float*)d_in[0];
    const float* Wf = (const float*)d_in[1];
    const float* bf = (const float*)d_in[2];
    const float* Wi = (const float*)d_in[3];
    const float* bi = (const float*)d_in[4];
    const float* Wc = (const float*)d_in[5];
    const float* bc = (const float*)d_in[6];
    const float* Wo = (const float*)d_in[7];
    const float* bo = (const float*)d_in[8];
    float* out = (float*)d_out;

    // ws layout: Gx fp32 [8192][2048] | slots u64 [2][2048]
    const size_t gx_elems = (size_t)R_TOTAL * T_STEPS;
    const size_t need = gx_elems * 4 + 2 * D_CELL * 8;
    if (ws_size < need) return;
    float* Gx    = (float*)d_ws;
    u64*   slots = (u64*)(Gx + gx_elems);

    lstm_init_kernel<<<16, 256, 0, stream>>>(slots);

    lstm_gx_kernel<<<2048, 256, 0, stream>>>(Wf, bf, Wi, bi, Wc, bc, Wo, bo,
                                             x, Gx);

    lstm_rec_kernel<<<NBLK, NTHR, 0, stream>>>(Wf, Wi, Wc, Wo, Gx, slots, out);
}

// Round 3
// 6434.057 us; speedup vs baseline: 2.0719x; 1.7456x over previous
//
#include <hip/hip_runtime.h>
#include <math.h>

#define D_IN    1024
#define D_CELL  2048
#define T_STEPS 2048
#define D_Z     3072            // D_IN + D_CELL
#define R_TOTAL (4 * D_CELL)    // 8192 gate rows
#define NBLK    256
#define NTHR    1024

typedef unsigned long long u64;

// ---------------------------------------------------------------------------
// init: zero the h-exchange slots (harness does NOT re-poison ws between
// timed replays; stale tags from a previous replay would satisfy polls).
// slots = u64[2][D_CELL], slot = (tag<<32)|f32bits(h)
// ---------------------------------------------------------------------------
__global__ void lstm_init_kernel(u64* __restrict__ slots) {
    int i = blockIdx.x * 256 + threadIdx.x;
    if (i < 2 * D_CELL) slots[i] = 0ull;
}

// ---------------------------------------------------------------------------
// Gx[r][t] = b[r] + sum_k W_g[d][k] * x[k][t]   (k < 1024, input part)
// 1D grid of 2048 blocks, XCD-aware decode: each XCD works on ONE t-half
// (same 4 MiB x tile -> fits its private 4 MiB L2). 256 threads, each
// handles 4 t-columns x 8 rows. W row loads are wave-uniform -> s_load.
// ---------------------------------------------------------------------------
__global__ __launch_bounds__(256) void lstm_gx_kernel(
    const float* __restrict__ Wf, const float* __restrict__ bf,
    const float* __restrict__ Wi, const float* __restrict__ bi,
    const float* __restrict__ Wc, const float* __restrict__ bc,
    const float* __restrict__ Wo, const float* __restrict__ bo,
    const float* __restrict__ x,  float* __restrict__ Gx)
{
    const int bid = blockIdx.x;          // 0..2047
    const int xcd = bid & 7;             // HW round-robin: bid%8 = XCD
    const int loc = bid >> 3;            // 0..255
    const int tx  = xcd >> 2;            // t-half 0/1 (4 XCDs per half)
    const int yb  = (xcd & 3) * 256 + loc;   // row-block 0..1023
    const int tid = threadIdx.x;
    const int t0  = tx * 1024 + tid * 4;
    const int r0  = yb * 8;
    const int g   = r0 >> 11;
    const int d0  = r0 & 2047;
    const float* W = (g == 0) ? Wf : (g == 1) ? Wi : (g == 2) ? Wc : Wo;
    const float* b = (g == 0) ? bf : (g == 1) ? bi : (g == 2) ? bc : bo;

    const float* wr0 = W + (size_t)(d0 + 0) * D_Z;
    const float* wr1 = W + (size_t)(d0 + 1) * D_Z;
    const float* wr2 = W + (size_t)(d0 + 2) * D_Z;
    const float* wr3 = W + (size_t)(d0 + 3) * D_Z;
    const float* wr4 = W + (size_t)(d0 + 4) * D_Z;
    const float* wr5 = W + (size_t)(d0 + 5) * D_Z;
    const float* wr6 = W + (size_t)(d0 + 6) * D_Z;
    const float* wr7 = W + (size_t)(d0 + 7) * D_Z;

    float4 acc[8];
#pragma unroll
    for (int jr = 0; jr < 8; ++jr) acc[jr] = make_float4(0.f, 0.f, 0.f, 0.f);

    for (int k = 0; k < D_IN; k += 4) {
        float4 xa = *(const float4*)(x + (size_t)(k + 0) * T_STEPS + t0);
        float4 xb = *(const float4*)(x + (size_t)(k + 1) * T_STEPS + t0);
        float4 xc = *(const float4*)(x + (size_t)(k + 2) * T_STEPS + t0);
        float4 xd = *(const float4*)(x + (size_t)(k + 3) * T_STEPS + t0);
        const float* wrs[8] = {wr0, wr1, wr2, wr3, wr4, wr5, wr6, wr7};
#pragma unroll
        for (int jr = 0; jr < 8; ++jr) {
            float4 w = *(const float4*)(wrs[jr] + k);   // wave-uniform
            acc[jr].x += w.x * xa.x + w.y * xb.x + w.z * xc.x + w.w * xd.x;
            acc[jr].y += w.x * xa.y + w.y * xb.y + w.z * xc.y + w.w * xd.y;
            acc[jr].z += w.x * xa.z + w.y * xb.z + w.z * xc.z + w.w * xd.z;
            acc[jr].w += w.x * xa.w + w.y * xb.w + w.z * xc.w + w.w * xd.w;
        }
    }

#pragma unroll
    for (int jr = 0; jr < 8; ++jr) {
        float bb = b[d0 + jr];
        float4 o = acc[jr];
        o.x += bb; o.y += bb; o.z += bb; o.w += bb;
        *(float4*)(Gx + (size_t)(r0 + jr) * T_STEPS + t0) = o;
    }
}

// ---------------------------------------------------------------------------
// Persistent recurrence kernel — EXACT round-0 skeleton (16 waves, 2 rows per
// wave, weight loads before the loop; the compiler keeps the 64 floats/lane
// on-chip by spilling them to AGPRs — do NOT add register-class constraints,
// round-2 showed "+v" asm forces scratch spills instead). Changes vs round 0
// are confined to the leaf segments of the serial chain:
//   - batched 2-slot poll (one combined tag check)
//   - cell state c in a register (was LDS cls[]: 2 LDS round-trips/step)
//   - fast activations via v_exp_f32/v_rcp_f32 (was libm expf/tanhf)
//   - h-slot publish BEFORE the out store
// ---------------------------------------------------------------------------
__global__ __launch_bounds__(NTHR, 4) void lstm_rec_kernel(
    const float* __restrict__ Wf, const float* __restrict__ Wi,
    const float* __restrict__ Wc, const float* __restrict__ Wo,
    const float* __restrict__ Gx, u64* __restrict__ slots,
    float* __restrict__ out)
{
    __shared__ float hs[D_CELL];     // h_{t-1}, fp32
    __shared__ float gdot[32];       // per-row reduced dots

    const int tid  = threadIdx.x;
    const int w    = tid >> 6;       // wave 0..15
    const int lane = tid & 63;
    const int r0   = 2 * w;          // rows r0, r0+1  (row = cell*4 + gate)

    // ---- load my two weight rows (fp32, stay on-chip in VGPRs/AGPRs) ----
    const int g0 = r0 & 3,        g1 = (r0 + 1) & 3;
    const int cl = r0 >> 2;                       // same cell for both rows
    const int d  = blockIdx.x * 8 + cl;           // global cell
    const float* Wb0 = ((g0 == 0) ? Wf : (g0 == 1) ? Wi : (g0 == 2) ? Wc : Wo)
                       + (size_t)d * D_Z + D_IN;
    const float* Wb1 = ((g1 == 0) ? Wf : (g1 == 1) ? Wi : (g1 == 2) ? Wc : Wo)
                       + (size_t)d * D_Z + D_IN;
    float4 wA[8], wB[8];
#pragma unroll
    for (int j = 0; j < 8; ++j) {
        wA[j] = *(const float4*)(Wb0 + j * 256 + lane * 4);
        wB[j] = *(const float4*)(Wb1 + j * 256 + lane * 4);
    }

    // Gx row base for lanes 0,1 (lane L handles row r0+L)
    const int myrow = r0 + (lane & 1);
    const size_t gxbase = (size_t)((myrow & 3) * D_CELL
                                   + blockIdx.x * 8 + (myrow >> 2)) * T_STEPS;

    float c = 0.f;                   // cell state (tid<8 threads own cell tid)
    const float L2E  = 1.442695041f;     // log2(e)
    const float L2E2 = 2.885390082f;     // 2*log2(e)

    for (int t = 0; t < T_STEPS; ++t) {
        // prefetch Gx early (independent of poll)
        float gx_pref = 0.f;
        if (lane < 2) gx_pref = Gx[gxbase + t];

        // ---- acquire h_{t-1}: batched poll of my 2 slots, stage into LDS ----
        if (t == 0) {
            hs[2 * tid]     = 0.f;
            hs[2 * tid + 1] = 0.f;
        } else {
            const u64* bp = slots + (size_t)(t & 1) * D_CELL + 2 * tid;
            const u64 tg = (u64)(unsigned)t << 32;
            u64 a, b;
            for (;;) {
                a = __hip_atomic_load(bp + 0, __ATOMIC_RELAXED,
                                      __HIP_MEMORY_SCOPE_AGENT);
                b = __hip_atomic_load(bp + 1, __ATOMIC_RELAXED,
                                      __HIP_MEMORY_SCOPE_AGENT);
                if ((((a ^ tg) | (b ^ tg)) >> 32) == 0) break;
                __builtin_amdgcn_s_sleep(1);
            }
            hs[2 * tid]     = __uint_as_float((unsigned)a);
            hs[2 * tid + 1] = __uint_as_float((unsigned)b);
        }
        __syncthreads();                          // sync A: hs ready

        // ---- two gate-row dot slices from on-chip weights ----
        float acc0 = 0.f, acc1 = 0.f;
#pragma unroll
        for (int j = 0; j < 8; ++j) {
            float4 h = *(const float4*)(hs + j * 256 + lane * 4);
            acc0 += wA[j].x * h.x + wA[j].y * h.y + wA[j].z * h.z + wA[j].w * h.w;
            acc1 += wB[j].x * h.x + wB[j].y * h.y + wB[j].z * h.z + wB[j].w * h.w;
        }
        // paired butterfly: even lanes -> row r0 sum, odd lanes -> row r0+1
        float vK = (lane & 1) ? acc1 : acc0;
        float vO = (lane & 1) ? acc0 : acc1;
        float v  = vK + __shfl_xor(vO, 1);
        v += __shfl_xor(v, 2);
        v += __shfl_xor(v, 4);
        v += __shfl_xor(v, 8);
        v += __shfl_xor(v, 16);
        v += __shfl_xor(v, 32);
        if (lane < 2) gdot[r0 + lane] = v + gx_pref;
        __syncthreads();                          // sync B: gdot ready

        // ---- activations: one thread per owned cell (fast exp2/rcp) ----
        if (tid < 8) {
            float gf = gdot[tid * 4 + 0], gi = gdot[tid * 4 + 1];
            float gc = gdot[tid * 4 + 2], go = gdot[tid * 4 + 3];
            float f    = __builtin_amdgcn_rcpf(
                             1.f + __builtin_amdgcn_exp2f(-L2E * gf));
            float ig   = __builtin_amdgcn_rcpf(
                             1.f + __builtin_amdgcn_exp2f(-L2E * gi));
            float o    = __builtin_amdgcn_rcpf(
                             1.f + __builtin_amdgcn_exp2f(-L2E * go));
            float cand = 1.f - 2.f * __builtin_amdgcn_rcpf(
                             __builtin_amdgcn_exp2f(L2E2 * gc) + 1.f);
            c = f * c + ig * cand;
            float tc   = 1.f - 2.f * __builtin_amdgcn_rcpf(
                             __builtin_amdgcn_exp2f(L2E2 * c) + 1.f);
            float hn = o * tc;
            if (t + 1 < T_STEPS) {                // publish FIRST
                u64 pk = ((u64)(unsigned)(t + 1) << 32)
                       | (u64)__float_as_uint(hn);
                __hip_atomic_store(
                    slots + (size_t)((t + 1) & 1) * D_CELL + blockIdx.x * 8 + tid,
                    pk, __ATOMIC_RELAXED, __HIP_MEMORY_SCOPE_AGENT);
            }
            out[(size_t)(blockIdx.x * 8 + tid) * T_STEPS + t] = hn;
        }
        // no third sync needed: hs writes for t+1 happen after this block's
        // compute reads (pre sync B); gdot/c for t+1 written after sync A(t+1)
    }
}

// ---------------------------------------------------------------------------
extern "C" void kernel_launch(void* const* d_in, const int* in_sizes, int n_in,
                              void* d_out, int out_size, void* d_ws, size_t ws_size,
                              hipStream_t stream) {
    const float* x  = (const float*)d_in[0];
    const float* Wf = (const float*)d_in[1];
    const float* bf = (const float*)d_in[2];
    const float* Wi = (const float*)d_in[3];
    const float* bi = (const float*)d_in[4];
    const float* Wc = (const float*)d_in[5];
    const float* bc = (const float*)d_in[6];
    const float* Wo = (const float*)d_in[7];
    const float* bo = (const float*)d_in[8];
    float* out = (float*)d_out;

    // ws layout: Gx fp32 [8192][2048] | slots u64 [2][2048]
    const size_t gx_elems = (size_t)R_TOTAL * T_STEPS;
    const size_t need = gx_elems * 4 + 2 * D_CELL * 8;
    if (ws_size < need) return;
    float* Gx    = (float*)d_ws;
    u64*   slots = (u64*)(Gx + gx_elems);

    lstm_init_kernel<<<16, 256, 0, stream>>>(slots);

    lstm_gx_kernel<<<2048, 256, 0, stream>>>(Wf, bf, Wi, bi, Wc, bc, Wo, bo,
                                             x, Gx);

    lstm_rec_kernel<<<NBLK, NTHR, 0, stream>>>(Wf, Wi, Wc, Wo, Gx, slots, out);
}